// Round 1
// baseline (1864.494 us; speedup 1.0000x reference)
//
#include <hip/hip_runtime.h>
#include <cstdint>
#include <cstddef>

// Problem constants (B=2, L=2048, D=1024, E=8, F=2048, TOP_K=2)
constexpr int T_TOK = 4096;      // B*L
constexpr int D_DIM = 1024;
constexpr int E_NUM = 8;
constexpr int F_DIM = 2048;
constexpr int C2F   = 4096;      // 2*F
constexpr int NPAIR = T_TOK * 2; // 8192 (token, slot) pairs

#define ALPHA_SW 1.702f
#define LIMIT_SW 9.0f

// ---------------- workspace layout (bytes) ----------------
// 0      counts[8]
// 32     cursor[8]
// 64     offsets[9]  (pad to 128)
// 128    sel[8192] int
// 32896  wts[8192] float
// 65664  pair_ts[8192] int        (compacted: value = t*2+slot)
// 98432  pos_of[8192] int         (inverse map)
// 131328 f_act[8192*2048] float   (67.1 MB)
// 67240192 y[8192*1024] float     (33.6 MB)   total ~96.2 MB
constexpr size_t OFF_COUNTS  = 0;
constexpr size_t OFF_CURSOR  = 32;
constexpr size_t OFF_OFFSETS = 64;
constexpr size_t OFF_SEL     = 128;
constexpr size_t OFF_WTS     = OFF_SEL + (size_t)NPAIR * 4;
constexpr size_t OFF_PAIRTS  = OFF_WTS + (size_t)NPAIR * 4;
constexpr size_t OFF_POSOF   = OFF_PAIRTS + (size_t)NPAIR * 4;
constexpr size_t OFF_FACT    = 131328;
constexpr size_t OFF_Y       = OFF_FACT + (size_t)NPAIR * F_DIM * 4;

// ---------------- K1: gate + top-2 + softmax + counts ----------------
__global__ __launch_bounds__(256) void gate_route_kernel(
    const float* __restrict__ x, const float* __restrict__ gate_w,
    int* __restrict__ sel, float* __restrict__ wts, int* __restrict__ counts) {
  int wave = threadIdx.x >> 6;
  int lane = threadIdx.x & 63;
  int t = blockIdx.x * 4 + wave;
  if (t >= T_TOK) return;

  double acc[E_NUM];
#pragma unroll
  for (int e = 0; e < E_NUM; ++e) acc[e] = 0.0;

  const float* xr = x + (size_t)t * D_DIM;
#pragma unroll 4
  for (int i = 0; i < D_DIM / 64; ++i) {
    int d = i * 64 + lane;
    float xv = xr[d];
    const float* gw = gate_w + (size_t)d * E_NUM;
    float4 ga = *(const float4*)gw;
    float4 gb = *(const float4*)(gw + 4);
    acc[0] += (double)xv * (double)ga.x;
    acc[1] += (double)xv * (double)ga.y;
    acc[2] += (double)xv * (double)ga.z;
    acc[3] += (double)xv * (double)ga.w;
    acc[4] += (double)xv * (double)gb.x;
    acc[5] += (double)xv * (double)gb.y;
    acc[6] += (double)xv * (double)gb.z;
    acc[7] += (double)xv * (double)gb.w;
  }
#pragma unroll
  for (int off = 32; off >= 1; off >>= 1) {
#pragma unroll
    for (int e = 0; e < E_NUM; ++e) acc[e] += __shfl_down(acc[e], off, 64);
  }
  if (lane == 0) {
    int b0 = 0;
#pragma unroll
    for (int e = 1; e < E_NUM; ++e)
      if (acc[e] > acc[b0]) b0 = e;
    int b1 = (b0 == 0) ? 1 : 0;
#pragma unroll
    for (int e = 0; e < E_NUM; ++e)
      if (e != b0 && acc[e] > acc[b1] && e != b1) {
        if (e < b1 && acc[e] == acc[b1]) continue;
        if (acc[e] > acc[b1]) b1 = e;
      }
    double p0 = 1.0 / (1.0 + exp(acc[b1] - acc[b0]));
    sel[t * 2 + 0] = b0;
    sel[t * 2 + 1] = b1;
    wts[t * 2 + 0] = (float)p0;
    wts[t * 2 + 1] = (float)(1.0 - p0);
    atomicAdd(&counts[b0], 1);
    atomicAdd(&counts[b1], 1);
  }
}

// ---------------- K2: exclusive prefix scan over 8 counts ----------------
__global__ void scan_kernel(const int* __restrict__ counts, int* __restrict__ offsets) {
  if (threadIdx.x == 0 && blockIdx.x == 0) {
    int s = 0;
    for (int e = 0; e < E_NUM; ++e) { offsets[e] = s; s += counts[e]; }
    offsets[E_NUM] = s;
  }
}

// ---------------- K3: scatter pairs into per-expert groups ----------------
__global__ __launch_bounds__(256) void scatter_kernel(
    const int* __restrict__ sel, const int* __restrict__ offsets,
    int* __restrict__ cursor, int* __restrict__ pair_ts, int* __restrict__ pos_of) {
  int p = blockIdx.x * 256 + threadIdx.x;
  if (p >= NPAIR) return;
  int e = sel[p];
  int idx = offsets[e] + atomicAdd(&cursor[e], 1);
  pair_ts[idx] = p;
  pos_of[p] = idx;
}

__device__ __forceinline__ float swiglu_f(float g, float v) {
  g = fminf(g, LIMIT_SW);
  v = fminf(fmaxf(v, -LIMIT_SW), LIMIT_SW);
  float s = 1.0f / (1.0f + expf(-ALPHA_SW * g));
  return g * s * (v + 1.0f);
}

// ---------------- K4: GEMM1 (h = x @ W1[e]^T + b1) fused SwiGLU ----------------
// grid: (C2F/64, 64, 8) ; block 256 ; 64x64 tile, K-chunk 16, 4x4 micro-tile
__global__ __launch_bounds__(256) void gemm1_swiglu_kernel(
    const float* __restrict__ x, const float* __restrict__ w1,
    const float* __restrict__ b1, const int* __restrict__ offsets,
    const int* __restrict__ pair_ts, float* __restrict__ f_act) {
  int e = blockIdx.z;
  int n_e = offsets[e + 1] - offsets[e];
  int row0 = blockIdx.y * 64;
  if (row0 >= n_e) return;
  int base = offsets[e];
  int c0 = blockIdx.x * 64;

  __shared__ float As[16][64];
  __shared__ float Bs[16][64];
  __shared__ int tok[64];

  int tid = threadIdx.x;
  if (tid < 64) {
    int r = row0 + tid;
    tok[tid] = (r < n_e) ? (pair_ts[base + r] >> 1) : -1;
  }
  __syncthreads();

  int lm = tid >> 2;          // 0..63 tile row/col for loads
  int lk = (tid & 3) * 4;     // k sub-offset
  int tx = tid & 15, ty = tid >> 4;

  float acc[4][4] = {};
  const float* brow = w1 + ((size_t)e * C2F + c0 + lm) * D_DIM;
  int tk = tok[lm];
  const float* arow = (tk >= 0) ? (x + (size_t)tk * D_DIM) : x;

  for (int kk = 0; kk < D_DIM; kk += 16) {
    float4 av = make_float4(0.f, 0.f, 0.f, 0.f);
    if (tk >= 0) av = *(const float4*)&arow[kk + lk];
    float4 bv = *(const float4*)&brow[kk + lk];
    As[lk + 0][lm] = av.x; As[lk + 1][lm] = av.y;
    As[lk + 2][lm] = av.z; As[lk + 3][lm] = av.w;
    Bs[lk + 0][lm] = bv.x; Bs[lk + 1][lm] = bv.y;
    Bs[lk + 2][lm] = bv.z; Bs[lk + 3][lm] = bv.w;
    __syncthreads();
#pragma unroll
    for (int k = 0; k < 16; ++k) {
      float4 a4 = *(const float4*)&As[k][ty * 4];
      float4 b4 = *(const float4*)&Bs[k][tx * 4];
      float am[4] = {a4.x, a4.y, a4.z, a4.w};
      float bm[4] = {b4.x, b4.y, b4.z, b4.w};
#pragma unroll
      for (int r = 0; r < 4; ++r)
#pragma unroll
        for (int j = 0; j < 4; ++j) acc[r][j] += am[r] * bm[j];
    }
    __syncthreads();
  }

  // epilogue: bias + swiglu; columns (c0+tx*4 .. +3) = two (g,v) pairs
  int cb = c0 + tx * 4;
  int fbase = cb >> 1;
  float4 bias = *(const float4*)&b1[(size_t)e * C2F + cb];
#pragma unroll
  for (int r = 0; r < 4; ++r) {
    int rl = row0 + ty * 4 + r;
    if (rl >= n_e) continue;
    float g0 = acc[r][0] + bias.x, v0 = acc[r][1] + bias.y;
    float g1 = acc[r][2] + bias.z, v1 = acc[r][3] + bias.w;
    float2 o;
    o.x = swiglu_f(g0, v0);
    o.y = swiglu_f(g1, v1);
    *(float2*)&f_act[(size_t)(base + rl) * F_DIM + fbase] = o;
  }
}

// ---------------- K5: GEMM2 (y = f_act @ W2[e]^T + b2) ----------------
// grid: (D/64, 64, 8)
__global__ __launch_bounds__(256) void gemm2_kernel(
    const float* __restrict__ f_act, const float* __restrict__ w2,
    const float* __restrict__ b2, const int* __restrict__ offsets,
    float* __restrict__ y) {
  int e = blockIdx.z;
  int n_e = offsets[e + 1] - offsets[e];
  int row0 = blockIdx.y * 64;
  if (row0 >= n_e) return;
  int base = offsets[e];
  int d0 = blockIdx.x * 64;

  __shared__ float As[16][64];
  __shared__ float Bs[16][64];

  int tid = threadIdx.x;
  int lm = tid >> 2;
  int lk = (tid & 3) * 4;
  int tx = tid & 15, ty = tid >> 4;

  float acc[4][4] = {};
  int ra = row0 + lm;
  int ra_c = (ra < n_e) ? ra : (n_e - 1);  // clamp to stay in-expert
  const float* arow = f_act + (size_t)(base + ra_c) * F_DIM;
  const float* brow = w2 + ((size_t)e * D_DIM + d0 + lm) * F_DIM;

  for (int kk = 0; kk < F_DIM; kk += 16) {
    float4 av = *(const float4*)&arow[kk + lk];
    float4 bv = *(const float4*)&brow[kk + lk];
    As[lk + 0][lm] = av.x; As[lk + 1][lm] = av.y;
    As[lk + 2][lm] = av.z; As[lk + 3][lm] = av.w;
    Bs[lk + 0][lm] = bv.x; Bs[lk + 1][lm] = bv.y;
    Bs[lk + 2][lm] = bv.z; Bs[lk + 3][lm] = bv.w;
    __syncthreads();
#pragma unroll
    for (int k = 0; k < 16; ++k) {
      float4 a4 = *(const float4*)&As[k][ty * 4];
      float4 b4 = *(const float4*)&Bs[k][tx * 4];
      float am[4] = {a4.x, a4.y, a4.z, a4.w};
      float bm[4] = {b4.x, b4.y, b4.z, b4.w};
#pragma unroll
      for (int r = 0; r < 4; ++r)
#pragma unroll
        for (int j = 0; j < 4; ++j) acc[r][j] += am[r] * bm[j];
    }
    __syncthreads();
  }

  int db = d0 + tx * 4;
  float4 bias = *(const float4*)&b2[(size_t)e * D_DIM + db];
#pragma unroll
  for (int r = 0; r < 4; ++r) {
    int rl = row0 + ty * 4 + r;
    if (rl >= n_e) continue;
    float4 o;
    o.x = acc[r][0] + bias.x;
    o.y = acc[r][1] + bias.y;
    o.z = acc[r][2] + bias.z;
    o.w = acc[r][3] + bias.w;
    *(float4*)&y[(size_t)(base + rl) * D_DIM + db] = o;
  }
}

// ---------------- K6: combine the two expert outputs per token ----------------
__global__ __launch_bounds__(256) void combine_kernel(
    const float* __restrict__ y, const int* __restrict__ pos_of,
    const float* __restrict__ wts, float* __restrict__ out) {
  int gid = blockIdx.x * 256 + threadIdx.x;
  int t = gid >> 8;            // 256 threads per token (D/4 = 256)
  int d4 = (gid & 255) * 4;
  if (t >= T_TOK) return;
  int p0 = pos_of[t * 2], p1 = pos_of[t * 2 + 1];
  float w0 = wts[t * 2], w1v = wts[t * 2 + 1];
  float4 a = *(const float4*)&y[(size_t)p0 * D_DIM + d4];
  float4 b = *(const float4*)&y[(size_t)p1 * D_DIM + d4];
  float4 o;
  o.x = w0 * a.x + w1v * b.x;
  o.y = w0 * a.y + w1v * b.y;
  o.z = w0 * a.z + w1v * b.z;
  o.w = w0 * a.w + w1v * b.w;
  *(float4*)&out[(size_t)t * D_DIM + d4] = o;
}

extern "C" void kernel_launch(void* const* d_in, const int* in_sizes, int n_in,
                              void* d_out, int out_size, void* d_ws, size_t ws_size,
                              hipStream_t stream) {
  const float* x      = (const float*)d_in[0];
  const float* gate_w = (const float*)d_in[1];
  const float* w1     = (const float*)d_in[2];
  const float* b1     = (const float*)d_in[3];
  const float* w2     = (const float*)d_in[4];
  const float* b2     = (const float*)d_in[5];
  float* out = (float*)d_out;

  char* ws = (char*)d_ws;
  int*   counts  = (int*)(ws + OFF_COUNTS);
  int*   cursor  = (int*)(ws + OFF_CURSOR);
  int*   offsets = (int*)(ws + OFF_OFFSETS);
  int*   sel     = (int*)(ws + OFF_SEL);
  float* wts     = (float*)(ws + OFF_WTS);
  int*   pair_ts = (int*)(ws + OFF_PAIRTS);
  int*   pos_of  = (int*)(ws + OFF_POSOF);
  float* f_act   = (float*)(ws + OFF_FACT);
  float* yb      = (float*)(ws + OFF_Y);

  hipMemsetAsync(d_ws, 0, 64, stream);  // zero counts + cursor
  gate_route_kernel<<<T_TOK / 4, 256, 0, stream>>>(x, gate_w, sel, wts, counts);
  scan_kernel<<<1, 64, 0, stream>>>(counts, offsets);
  scatter_kernel<<<NPAIR / 256, 256, 0, stream>>>(sel, offsets, cursor, pair_ts, pos_of);
  gemm1_swiglu_kernel<<<dim3(C2F / 64, 64, E_NUM), 256, 0, stream>>>(
      x, w1, b1, offsets, pair_ts, f_act);
  gemm2_kernel<<<dim3(D_DIM / 64, 64, E_NUM), 256, 0, stream>>>(
      f_act, w2, b2, offsets, yb);
  combine_kernel<<<T_TOK, 256, 0, stream>>>(yb, pos_of, wts, out);
}

// Round 2
// 606.115 us; speedup vs baseline: 3.0761x; 3.0761x over previous
//
#include <hip/hip_runtime.h>
#include <cstdint>
#include <cstddef>

// Problem constants (B=2, L=2048, D=1024, E=8, F=2048, TOP_K=2)
constexpr int T_TOK = 4096;      // B*L
constexpr int D_DIM = 1024;
constexpr int E_NUM = 8;
constexpr int F_DIM = 2048;
constexpr int C2F   = 4096;      // 2*F
constexpr int NPAIR = T_TOK * 2; // 8192 (token, slot) pairs

#define ALPHA_SW 1.702f
#define LIMIT_SW 9.0f

// ---------------- workspace layout (bytes) ----------------
constexpr size_t OFF_COUNTS  = 0;
constexpr size_t OFF_CURSOR  = 32;
constexpr size_t OFF_OFFSETS = 64;
constexpr size_t OFF_SEL     = 128;
constexpr size_t OFF_WTS     = OFF_SEL + (size_t)NPAIR * 4;      // 32896
constexpr size_t OFF_PAIRTS  = OFF_WTS + (size_t)NPAIR * 4;      // 65664
constexpr size_t OFF_FACT    = 98432;                            // f_act bf16 [8192][2048]
constexpr size_t SZ_FACT     = (size_t)NPAIR * F_DIM * 2;        // 33.55 MB
constexpr size_t OFF_XG      = OFF_FACT + SZ_FACT;               // xg bf16 [8192][1024]
constexpr size_t SZ_XG       = (size_t)NPAIR * D_DIM * 2;        // 16.78 MB
constexpr size_t OFF_WB      = OFF_XG + SZ_XG;                   // weight bf16 buffer
constexpr size_t SZ_W1B      = (size_t)E_NUM * C2F * D_DIM * 2;  // 67.11 MB
constexpr size_t SZ_W2B      = (size_t)E_NUM * D_DIM * F_DIM * 2;// 33.55 MB
constexpr size_t NEED_FAST   = OFF_WB + SZ_W1B;                  // 117.5 MB
// slow path needs OFF_WB + SZ_W2B = 84.0 MB (< 100.8 MB proven available)

typedef __bf16 bf16x8 __attribute__((ext_vector_type(8)));
typedef float  f32x4  __attribute__((ext_vector_type(4)));

// round-half-up f32->bf16 (cheap: add + shift / perm-pack)
__device__ __forceinline__ uint16_t bf16h(float f) {
  return (uint16_t)((__float_as_uint(f) + 0x8000u) >> 16);
}
__device__ __forceinline__ uint32_t pack2(float lo, float hi) {
  uint32_t ua = __float_as_uint(lo) + 0x8000u;
  uint32_t ub = __float_as_uint(hi) + 0x8000u;
  return __builtin_amdgcn_perm(ub, ua, 0x07060302); // {ub.hi16, ua.hi16}
}

// async global -> LDS, 16B per lane; lds must be wave-uniform base
__device__ __forceinline__ void gld_lds16(const uint16_t* g, uint16_t* l) {
  __builtin_amdgcn_global_load_lds(
      (const __attribute__((address_space(1))) unsigned int*)g,
      (__attribute__((address_space(3))) unsigned int*)l,
      16, 0, 0);
}

__device__ __forceinline__ float swiglu_f(float g, float v) {
  g = fminf(g, LIMIT_SW);
  v = fminf(fmaxf(v, -LIMIT_SW), LIMIT_SW);
  float s = 1.0f / (1.0f + expf(-ALPHA_SW * g));
  return g * s * (v + 1.0f);
}

// ---------------- K1: gate + top-2 + softmax + counts (fp64 for exact routing) ----------------
__global__ __launch_bounds__(256) void gate_route_kernel(
    const float* __restrict__ x, const float* __restrict__ gate_w,
    int* __restrict__ sel, float* __restrict__ wts, int* __restrict__ counts) {
  int wave = threadIdx.x >> 6;
  int lane = threadIdx.x & 63;
  int t = blockIdx.x * 4 + wave;
  if (t >= T_TOK) return;

  double acc[E_NUM];
#pragma unroll
  for (int e = 0; e < E_NUM; ++e) acc[e] = 0.0;

  const float* xr = x + (size_t)t * D_DIM;
#pragma unroll 4
  for (int i = 0; i < D_DIM / 64; ++i) {
    int d = i * 64 + lane;
    float xv = xr[d];
    const float* gw = gate_w + (size_t)d * E_NUM;
    float4 ga = *(const float4*)gw;
    float4 gb = *(const float4*)(gw + 4);
    acc[0] += (double)xv * (double)ga.x;
    acc[1] += (double)xv * (double)ga.y;
    acc[2] += (double)xv * (double)ga.z;
    acc[3] += (double)xv * (double)ga.w;
    acc[4] += (double)xv * (double)gb.x;
    acc[5] += (double)xv * (double)gb.y;
    acc[6] += (double)xv * (double)gb.z;
    acc[7] += (double)xv * (double)gb.w;
  }
#pragma unroll
  for (int off = 32; off >= 1; off >>= 1) {
#pragma unroll
    for (int e = 0; e < E_NUM; ++e) acc[e] += __shfl_down(acc[e], off, 64);
  }
  if (lane == 0) {
    int b0 = 0;
#pragma unroll
    for (int e = 1; e < E_NUM; ++e)
      if (acc[e] > acc[b0]) b0 = e;
    int b1 = (b0 == 0) ? 1 : 0;
#pragma unroll
    for (int e = 0; e < E_NUM; ++e)
      if (e != b0 && acc[e] > acc[b1] && e != b1) {
        if (e < b1 && acc[e] == acc[b1]) continue;
        if (acc[e] > acc[b1]) b1 = e;
      }
    double p0 = 1.0 / (1.0 + exp(acc[b1] - acc[b0]));
    sel[t * 2 + 0] = b0;
    sel[t * 2 + 1] = b1;
    wts[t * 2 + 0] = (float)p0;
    wts[t * 2 + 1] = (float)(1.0 - p0);
    atomicAdd(&counts[b0], 1);
    atomicAdd(&counts[b1], 1);
  }
}

// ---------------- K2: exclusive prefix scan over 8 counts ----------------
__global__ void scan_kernel(const int* __restrict__ counts, int* __restrict__ offsets) {
  if (threadIdx.x == 0 && blockIdx.x == 0) {
    int s = 0;
    for (int e = 0; e < E_NUM; ++e) { offsets[e] = s; s += counts[e]; }
    offsets[E_NUM] = s;
  }
}

// ---------------- K3: scatter pairs into per-expert groups ----------------
__global__ __launch_bounds__(256) void scatter_kernel(
    const int* __restrict__ sel, const int* __restrict__ offsets,
    int* __restrict__ cursor, int* __restrict__ pair_ts) {
  int p = blockIdx.x * 256 + threadIdx.x;
  if (p >= NPAIR) return;
  int e = sel[p];
  int idx = offsets[e] + atomicAdd(&cursor[e], 1);
  pair_ts[idx] = p;
}

// ---------------- K4: gather x rows -> compacted bf16 ----------------
__global__ __launch_bounds__(256) void gather_x_kernel(
    const float* __restrict__ x, const int* __restrict__ pair_ts,
    uint16_t* __restrict__ xg) {
  int p = blockIdx.x;
  int t = pair_ts[p] >> 1;
  int d = threadIdx.x * 4;
  float4 v = *(const float4*)&x[(size_t)t * D_DIM + d];
  uint2 o;
  o.x = pack2(v.x, v.y);
  o.y = pack2(v.z, v.w);
  *(uint2*)&xg[(size_t)p * D_DIM + d] = o;
}

// ---------------- K5: f32 -> bf16 bulk convert ----------------
__global__ __launch_bounds__(256) void cvt_bf16_kernel(
    const float* __restrict__ src, uint16_t* __restrict__ dst, int n4) {
  int i = blockIdx.x * 256 + threadIdx.x;
  if (i >= n4) return;
  float4 v = ((const float4*)src)[i];
  uint2 o;
  o.x = pack2(v.x, v.y);
  o.y = pack2(v.z, v.w);
  ((uint2*)dst)[i] = o;
}

// ---------------- K6: GEMM1  f_act = swiglu(xg @ w1[e]^T + b1) ----------------
// 128x128 tile, BK=32, 4 waves (2x2), 4x4 MFMA accs/wave. NT form: both A,B K-contiguous.
template<bool BPRE>
__global__ __launch_bounds__(256) void gemm1_kernel(
    const uint16_t* __restrict__ xg, const float* __restrict__ w1f,
    const uint16_t* __restrict__ w1b, const float* __restrict__ b1,
    const int* __restrict__ offsets, uint16_t* __restrict__ f_act) {
  const int e = blockIdx.z;
  const int base = offsets[e];
  const int n_e = offsets[e + 1] - base;
  const int row0 = blockIdx.y * 128;
  if (row0 >= n_e) return;
  const int c0 = blockIdx.x * 128;

  __shared__ uint16_t As[128 * 32];
  __shared__ uint16_t Bs[128 * 32];

  const int tid = threadIdx.x;
  const int lane = tid & 63;
  const int wv = tid >> 6;
  const int wm = wv & 1, wn = wv >> 1;

  // A staging: round r, wave wv covers rows r*64 + wv*16 + (lane>>2); 16B per lane
  int ag0 = base + row0 + wv * 16 + (lane >> 2); if (ag0 > NPAIR - 1) ag0 = NPAIR - 1;
  int ag1 = ag0 + 64;                            if (ag1 > NPAIR - 1) ag1 = NPAIR - 1;
  const uint16_t* agp0 = xg + (size_t)ag0 * D_DIM + (lane & 3) * 8;
  const uint16_t* agp1 = xg + (size_t)ag1 * D_DIM + (lane & 3) * 8;
  uint16_t* alds0 = &As[(wv * 16) * 32];
  uint16_t* alds1 = &As[(64 + wv * 16) * 32];

  const uint16_t* bgp0 = nullptr; const uint16_t* bgp1 = nullptr;
  const float* bf0 = nullptr; const float* bf1 = nullptr;
  uint16_t* blds0 = &Bs[(wv * 16) * 32];
  uint16_t* blds1 = &Bs[(64 + wv * 16) * 32];
  if (BPRE) {
    bgp0 = w1b + ((size_t)e * C2F + c0 + wv * 16 + (lane >> 2)) * D_DIM + (lane & 3) * 8;
    bgp1 = bgp0 + (size_t)64 * D_DIM;
  } else {
    bf0 = w1f + ((size_t)e * C2F + c0 + (tid >> 2)) * D_DIM + (tid & 3) * 8;
    bf1 = bf0 + (size_t)64 * D_DIM;
  }

  f32x4 acc[4][4];
#pragma unroll
  for (int mi = 0; mi < 4; ++mi)
#pragma unroll
    for (int ni = 0; ni < 4; ++ni) acc[mi][ni] = (f32x4){0.f, 0.f, 0.f, 0.f};

  const int ar = lane & 15;
  const int ak = (lane >> 4) * 8;

  for (int kk = 0; kk < D_DIM; kk += 32) {
    float4 x0, x1, y0, y1;
    if (!BPRE) {
      x0 = *(const float4*)(bf0 + kk);
      x1 = *(const float4*)(bf0 + kk + 4);
      y0 = *(const float4*)(bf1 + kk);
      y1 = *(const float4*)(bf1 + kk + 4);
    }
    __syncthreads();  // previous iter's LDS reads complete
    gld_lds16(agp0 + kk, alds0);
    gld_lds16(agp1 + kk, alds1);
    if (BPRE) {
      gld_lds16(bgp0 + kk, blds0);
      gld_lds16(bgp1 + kk, blds1);
    } else {
      uint4 p0, p1;
      p0.x = pack2(x0.x, x0.y); p0.y = pack2(x0.z, x0.w);
      p0.z = pack2(x1.x, x1.y); p0.w = pack2(x1.z, x1.w);
      p1.x = pack2(y0.x, y0.y); p1.y = pack2(y0.z, y0.w);
      p1.z = pack2(y1.x, y1.y); p1.w = pack2(y1.z, y1.w);
      *(uint4*)&Bs[(tid >> 2) * 32 + (tid & 3) * 8] = p0;
      *(uint4*)&Bs[(64 + (tid >> 2)) * 32 + (tid & 3) * 8] = p1;
    }
    __syncthreads();  // staging visible

    bf16x8 af[4], bfv[4];
#pragma unroll
    for (int mi = 0; mi < 4; ++mi)
      af[mi] = *(const bf16x8*)&As[(wm * 64 + mi * 16 + ar) * 32 + ak];
#pragma unroll
    for (int ni = 0; ni < 4; ++ni)
      bfv[ni] = *(const bf16x8*)&Bs[(wn * 64 + ni * 16 + ar) * 32 + ak];
#pragma unroll
    for (int mi = 0; mi < 4; ++mi)
#pragma unroll
      for (int ni = 0; ni < 4; ++ni)
        acc[mi][ni] = __builtin_amdgcn_mfma_f32_16x16x32_bf16(af[mi], bfv[ni], acc[mi][ni], 0, 0, 0);
  }

  // epilogue: bias + swiglu pairing via shfl_xor(1); even cols hold g, odd v
  const float* b1e = b1 + (size_t)e * C2F + c0;
#pragma unroll
  for (int ni = 0; ni < 4; ++ni) {
    int col_l = wn * 64 + ni * 16 + (lane & 15);
    float bias = b1e[col_l];
#pragma unroll
    for (int mi = 0; mi < 4; ++mi)
#pragma unroll
      for (int r = 0; r < 4; ++r) {
        float val = acc[mi][ni][r] + bias;
        float oth = __shfl_xor(val, 1);
        float g = (lane & 1) ? oth : val;
        float v = (lane & 1) ? val : oth;
        float f = swiglu_f(g, v);
        int row_l = wm * 64 + mi * 16 + (lane >> 4) * 4 + r;
        if (!(lane & 1) && (row0 + row_l) < n_e)
          f_act[(size_t)(base + row0 + row_l) * F_DIM + ((c0 + col_l) >> 1)] = bf16h(f);
      }
  }
}

// ---------------- K7: GEMM2  out[t] += wt * (f_act @ w2[e]^T + b2) ----------------
__global__ __launch_bounds__(256) void gemm2_kernel(
    const uint16_t* __restrict__ f_act, const uint16_t* __restrict__ w2b,
    const float* __restrict__ b2, const int* __restrict__ offsets,
    const int* __restrict__ pair_ts, const float* __restrict__ wts,
    float* __restrict__ out) {
  const int e = blockIdx.z;
  const int base = offsets[e];
  const int n_e = offsets[e + 1] - base;
  const int row0 = blockIdx.y * 128;
  if (row0 >= n_e) return;
  const int c0 = blockIdx.x * 128;

  __shared__ uint16_t As[128 * 32];
  __shared__ uint16_t Bs[128 * 32];

  const int tid = threadIdx.x;
  const int lane = tid & 63;
  const int wv = tid >> 6;
  const int wm = wv & 1, wn = wv >> 1;

  int ag0 = base + row0 + wv * 16 + (lane >> 2); if (ag0 > NPAIR - 1) ag0 = NPAIR - 1;
  int ag1 = ag0 + 64;                            if (ag1 > NPAIR - 1) ag1 = NPAIR - 1;
  const uint16_t* agp0 = f_act + (size_t)ag0 * F_DIM + (lane & 3) * 8;
  const uint16_t* agp1 = f_act + (size_t)ag1 * F_DIM + (lane & 3) * 8;
  const uint16_t* bgp0 = w2b + ((size_t)e * D_DIM + c0 + wv * 16 + (lane >> 2)) * F_DIM + (lane & 3) * 8;
  const uint16_t* bgp1 = bgp0 + (size_t)64 * F_DIM;
  uint16_t* alds0 = &As[(wv * 16) * 32];
  uint16_t* alds1 = &As[(64 + wv * 16) * 32];
  uint16_t* blds0 = &Bs[(wv * 16) * 32];
  uint16_t* blds1 = &Bs[(64 + wv * 16) * 32];

  f32x4 acc[4][4];
#pragma unroll
  for (int mi = 0; mi < 4; ++mi)
#pragma unroll
    for (int ni = 0; ni < 4; ++ni) acc[mi][ni] = (f32x4){0.f, 0.f, 0.f, 0.f};

  const int ar = lane & 15;
  const int ak = (lane >> 4) * 8;

  for (int kk = 0; kk < F_DIM; kk += 32) {
    __syncthreads();
    gld_lds16(agp0 + kk, alds0);
    gld_lds16(agp1 + kk, alds1);
    gld_lds16(bgp0 + kk, blds0);
    gld_lds16(bgp1 + kk, blds1);
    __syncthreads();

    bf16x8 af[4], bfv[4];
#pragma unroll
    for (int mi = 0; mi < 4; ++mi)
      af[mi] = *(const bf16x8*)&As[(wm * 64 + mi * 16 + ar) * 32 + ak];
#pragma unroll
    for (int ni = 0; ni < 4; ++ni)
      bfv[ni] = *(const bf16x8*)&Bs[(wn * 64 + ni * 16 + ar) * 32 + ak];
#pragma unroll
    for (int mi = 0; mi < 4; ++mi)
#pragma unroll
      for (int ni = 0; ni < 4; ++ni)
        acc[mi][ni] = __builtin_amdgcn_mfma_f32_16x16x32_bf16(af[mi], bfv[ni], acc[mi][ni], 0, 0, 0);
  }

  // epilogue: bias + weighted atomic scatter into out
  float bias4[4]; int d4a[4];
#pragma unroll
  for (int ni = 0; ni < 4; ++ni) {
    d4a[ni] = c0 + wn * 64 + ni * 16 + (lane & 15);
    bias4[ni] = b2[(size_t)e * D_DIM + d4a[ni]];
  }
#pragma unroll
  for (int mi = 0; mi < 4; ++mi)
#pragma unroll
    for (int r = 0; r < 4; ++r) {
      int grow = row0 + wm * 64 + mi * 16 + (lane >> 4) * 4 + r;
      if (grow >= n_e) continue;
      int pp = pair_ts[base + grow];
      float wt = wts[pp];
      size_t ob = (size_t)(pp >> 1) * D_DIM;
#pragma unroll
      for (int ni = 0; ni < 4; ++ni)
        atomicAdd(&out[ob + d4a[ni]], wt * (acc[mi][ni][r] + bias4[ni]));
    }
}

extern "C" void kernel_launch(void* const* d_in, const int* in_sizes, int n_in,
                              void* d_out, int out_size, void* d_ws, size_t ws_size,
                              hipStream_t stream) {
  const float* x      = (const float*)d_in[0];
  const float* gate_w = (const float*)d_in[1];
  const float* w1     = (const float*)d_in[2];
  const float* b1     = (const float*)d_in[3];
  const float* w2     = (const float*)d_in[4];
  const float* b2     = (const float*)d_in[5];
  float* out = (float*)d_out;

  char* ws = (char*)d_ws;
  int*      counts  = (int*)(ws + OFF_COUNTS);
  int*      cursor  = (int*)(ws + OFF_CURSOR);
  int*      offsets = (int*)(ws + OFF_OFFSETS);
  int*      sel     = (int*)(ws + OFF_SEL);
  float*    wts     = (float*)(ws + OFF_WTS);
  int*      pair_ts = (int*)(ws + OFF_PAIRTS);
  uint16_t* f_act   = (uint16_t*)(ws + OFF_FACT);
  uint16_t* xg      = (uint16_t*)(ws + OFF_XG);
  uint16_t* wb      = (uint16_t*)(ws + OFF_WB);

  const bool fast = ws_size >= NEED_FAST;  // constant across calls -> graph-safe

  hipMemsetAsync(d_ws, 0, 64, stream);
  hipMemsetAsync(d_out, 0, (size_t)out_size * sizeof(float), stream);
  gate_route_kernel<<<T_TOK / 4, 256, 0, stream>>>(x, gate_w, sel, wts, counts);
  scan_kernel<<<1, 64, 0, stream>>>(counts, offsets);
  scatter_kernel<<<NPAIR / 256, 256, 0, stream>>>(sel, offsets, cursor, pair_ts);
  gather_x_kernel<<<NPAIR, 256, 0, stream>>>(x, pair_ts, xg);
  if (fast) {
    cvt_bf16_kernel<<<(E_NUM * C2F * D_DIM / 4) / 256, 256, 0, stream>>>(w1, wb, E_NUM * C2F * D_DIM / 4);
    gemm1_kernel<true><<<dim3(C2F / 128, 64, E_NUM), 256, 0, stream>>>(xg, w1, wb, b1, offsets, f_act);
  } else {
    gemm1_kernel<false><<<dim3(C2F / 128, 64, E_NUM), 256, 0, stream>>>(xg, w1, wb, b1, offsets, f_act);
  }
  // w2 conversion reuses wb (w1b dead after gemm1; stream-ordered)
  cvt_bf16_kernel<<<(E_NUM * D_DIM * F_DIM / 4) / 256, 256, 0, stream>>>(w2, wb, E_NUM * D_DIM * F_DIM / 4);
  gemm2_kernel<<<dim3(D_DIM / 128, 64, E_NUM), 256, 0, stream>>>(f_act, wb, b2, offsets, pair_ts, wts, out);
}